// Round 1
// baseline (1576.185 us; speedup 1.0000x reference)
//
#include <hip/hip_runtime.h>

// SGM-style min-sum message passing, 4 directions, dense 21x21 label context.
// out = sum_d L_d - 3u, computed as:
//   H-kernel: pass0 (L->R): out = L_hf          (plain store, covers every element)
//             pass1 (R->L): out += L_hb - u
//   V-kernel: pass0 (T->B): out += L_vf - u
//             pass1 (B->T): out += L_vb - u
// Each scan-line task owns a disjoint slice of out; fwd/bwd of one line run
// sequentially in the same wave, and the two kernels are stream-ordered, so
// there are no write races and no atomics.
//
// Layout: 21 lanes per line (lane = label), 3 lines per 64-thread block.
// Per-step all-to-all of the 21 L values goes through a 24-float padded LDS
// row: 1 ds_write_b32 + 6 ds_read_b128 (broadcast within a line-group =
// conflict-free). Single-wave blocks => wave-synchronous exchange, no
// s_barrier (and no vmcnt(0) drain) in the inner loop; a wave_barrier pins
// the compiler's ordering. LDS ops within one wave execute in order.

#define DLBL 21
#define SP 512
#define NB 4
#define BIGF 1e30f

template<int AXIS>   // 0: scan over w (dirs 0,1) ; 1: scan over h (dirs 2,3)
__global__ __launch_bounds__(64)
void sweep_kernel(const float* __restrict__ unary,
                  const float* __restrict__ ew,
                  const float* __restrict__ Vmat,
                  float* __restrict__ out)
{
    __shared__ float xch[4][24];           // 4 line slots (slot 3 = junk lane), pad 24
    const int lane = threadIdx.x;          // 0..63
    const int g    = lane / DLBL;          // line-in-block 0..2 (3 = idle lane 63)
    const int s    = lane - g * DLBL;      // label 0..20
    int lineId = blockIdx.x * 3 + (g < 3 ? g : 0);
    const bool valid = (g < 3) && (lineId < NB * SP);
    if (lineId >= NB * SP) lineId = NB * SP - 1;   // clamp tail, stores predicated off
    const int b = lineId >> 9;             // /512
    const int p = lineId & (SP - 1);       // h for AXIS 0, w for AXIS 1

    // V column for this lane's output label: Vc[j] = V[j][s]
    float Vc[DLBL];
#pragma unroll
    for (int j = 0; j < DLBL; ++j) Vc[j] = Vmat[j * DLBL + s];

    long ubase, ustep;
    if (AXIS == 0) { ubase = ((long)(b * DLBL + s) * SP + p) * SP; ustep = 1; }
    else           { ubase = (long)(b * DLBL + s) * SP * SP + p;   ustep = SP; }

    for (int pass = 0; pass < 2; ++pass) {
        const int dir = (AXIS == 0 ? 0 : 2) + pass;
        long wbase, wstep;
        if (AXIS == 0) { wbase = ((long)(b * 4 + dir) * SP + p) * SP; wstep = 1; }
        else           { wbase = (long)(b * 4 + dir) * SP * SP + p;   wstep = SP; }

        const long uoff = pass ? -ustep : ustep;
        const long woff = pass ? -wstep : wstep;
        const float* up = unary + ubase + (pass ? (long)(SP - 1) * ustep : 0);
        const float* wp = ew    + wbase + (pass ? (long)(SP - 1) * wstep : 0);
        float*       op = out   + ubase + (pass ? (long)(SP - 1) * ustep : 0);

        // t = 0 (border): L = u
        float u_t = *up;
        float cur = u_t;
        if (valid) {
            if (AXIS == 0 && pass == 0) *op = cur;
            else                        *op = *op + cur - u_t;   // cur - u_t == 0, keeps code uniform
        }
        up += uoff; wp += woff; op += uoff;

        for (int t = 1; t < SP; ++t) {
            u_t = *up;
            const float w_t = *wp;
            float o_prev = 0.0f;
            if (valid && !(AXIS == 0 && pass == 0)) o_prev = *op;  // RMW load, off the DP chain

            // wave-synchronous all-to-all of the 21 previous L values
            xch[g][s] = cur;
            __builtin_amdgcn_wave_barrier();
            float Lp[24];
#pragma unroll
            for (int q = 0; q < 6; ++q)
                ((float4*)Lp)[q] = ((const float4*)(&xch[g][0]))[q];
            __builtin_amdgcn_wave_barrier();

            float m0 = BIGF, m1 = BIGF, m2 = BIGF;
#pragma unroll
            for (int j = 0; j < 7; ++j)   m0 = fminf(m0, fmaf(w_t, Vc[j],      Lp[j]));
#pragma unroll
            for (int j = 7; j < 14; ++j)  m1 = fminf(m1, fmaf(w_t, Vc[j],      Lp[j]));
#pragma unroll
            for (int j = 14; j < 21; ++j) m2 = fminf(m2, fmaf(w_t, Vc[j],      Lp[j]));
            cur = u_t + fminf(fminf(m0, m1), m2);

            if (valid) {
                if (AXIS == 0 && pass == 0) *op = cur;           // store L_hf
                else                        *op = o_prev + cur - u_t;
            }
            up += uoff; wp += woff; op += uoff;
        }
    }
}

extern "C" void kernel_launch(void* const* d_in, const int* in_sizes, int n_in,
                              void* d_out, int out_size, void* d_ws, size_t ws_size,
                              hipStream_t stream) {
    const float* unary = (const float*)d_in[0];   // (4,1,21,512,512) f32
    const float* ew    = (const float*)d_in[1];   // (4,4,512,512)   f32
    const float* Vmat  = (const float*)d_in[2];   // (21,21)         f32
    float* o = (float*)d_out;                     // (4,1,21,512,512) f32

    const int nLines = NB * SP;                   // 2048 per axis
    const int grid = (nLines + 2) / 3;            // 683 blocks, 3 lines each
    dim3 gridDim_(grid), blockDim_(64);
    sweep_kernel<0><<<gridDim_, blockDim_, 0, stream>>>(unary, ew, Vmat, o);
    sweep_kernel<1><<<gridDim_, blockDim_, 0, stream>>>(unary, ew, Vmat, o);
}